// Round 7
// baseline (113.255 us; speedup 1.0000x reference)
//
#include <hip/hip_runtime.h>

typedef short short8 __attribute__((ext_vector_type(8)));
typedef float floatx4 __attribute__((ext_vector_type(4)));

// Native bf16 conversion: compiler emits packed v_cvt_pk_bf16_f32 (RTNE).
__device__ __forceinline__ short f2bf(float f) {
    __bf16 h = (__bf16)f;
    return __builtin_bit_cast(short, h);
}

// Convert lora_A (4096x64) and lora_B (64x4096) fp32 -> bf16 in MFMA fragment
// layout for mfma_f32_16x16x32_bf16:
//   lane l holds elem[k][c] with c = l&15, k = 8*(l>>4) + j, j=0..7
__global__ __launch_bounds__(256) void conv_ab(
    const float* __restrict__ A, const float* __restrict__ B,
    short* __restrict__ Abf, short* __restrict__ Bbf) {
    int i = blockIdx.x * 256 + threadIdx.x;   // 0 .. 262143
    int j    = i & 7;
    int lane = (i >> 3) & 63;
    int hi   = i >> 9;                        // A: ks*4+nt ; B: ct*2+ks
    int krow = 8 * (lane >> 4) + j;
    int cc   = lane & 15;
    {   // A fragments
        int ks = hi >> 2, nt = hi & 3;
        int k = ks * 32 + krow;
        int c = nt * 16 + cc;
        Abf[i] = f2bf(A[(size_t)k * 64 + c]);
    }
    {   // B fragments
        int ct = hi >> 1, ks = hi & 1;
        int k = ks * 32 + krow;
        int c = ct * 16 + cc;
        Bbf[i] = f2bf(B[(size_t)k * 4096 + c]);
    }
}

// Fused, 256 threads = 4 waves per block of 16 rows.
//   phase 1: t[16][64] = x[rows]@A, split-K 1024/wave, explicit 1-ahead prefetch.
//   phase 2: out = (t@B)*tw*2, operand-swapped mfma -> float4 NT stores,
//            explicit 1-ahead prefetch of the next tile's 8 B-fragments.
__global__ __launch_bounds__(256, 4) void fused(
    const float* __restrict__ x, const float* __restrict__ tw,
    const short* __restrict__ Abf, const short* __restrict__ Bbf,
    float* __restrict__ out) {
    __shared__ float red[4][16][65];      // per-wave f32 partials (16.6 KB)
    __shared__ short tl[16][80];          // reduced t, bf16 (2.5 KB)

    const int lane = threadIdx.x & 63;
    const int wave = threadIdx.x >> 6;    // 0..3
    const int rowbase = blockIdx.x * 16;
    const int rrow = lane & 15;
    const int kgrp = lane >> 4;           // 0..3
    const int kofs = kgrp * 8;

    // ---------------- phase 1: t = x @ A, split-K 1024 per wave ----------------
    {
        const int row = rowbase + rrow;
        const bool active = (tw[row] != 0.0f);
        const floatx4* xv = (const floatx4*)(x + (size_t)row * 4096 + wave * 1024 + kofs);
        // Abf8[(ksg*4 + nt)*64 + lane], ksg = wave*32 + ks
        const short8* ap = (const short8*)Abf + (size_t)wave * 8192 + lane;

        floatx4 acc0 = {0,0,0,0}, acc1 = {0,0,0,0}, acc2 = {0,0,0,0}, acc3 = {0,0,0,0};

        // prologue: loads for ks = 0
        floatx4 cx0 = {0,0,0,0}, cx1 = {0,0,0,0};
        if (active) { cx0 = xv[0]; cx1 = xv[1]; }
        short8 cb0 = ap[0], cb1 = ap[64], cb2 = ap[128], cb3 = ap[192];

        #pragma unroll 4
        for (int ks = 0; ks < 32; ++ks) {
            // prefetch ks+1 (clamped; last iter re-loads ks=31, harmless)
            const int kn = (ks + 1 < 32) ? ks + 1 : 31;
            floatx4 nx0 = {0,0,0,0}, nx1 = {0,0,0,0};
            if (active) { nx0 = xv[kn * 8]; nx1 = xv[kn * 8 + 1]; }
            short8 nb0 = ap[kn * 256 + 0 * 64];
            short8 nb1 = ap[kn * 256 + 1 * 64];
            short8 nb2 = ap[kn * 256 + 2 * 64];
            short8 nb3 = ap[kn * 256 + 3 * 64];

            short8 xa;
            xa[0] = f2bf(cx0[0]); xa[1] = f2bf(cx0[1]);
            xa[2] = f2bf(cx0[2]); xa[3] = f2bf(cx0[3]);
            xa[4] = f2bf(cx1[0]); xa[5] = f2bf(cx1[1]);
            xa[6] = f2bf(cx1[2]); xa[7] = f2bf(cx1[3]);

            acc0 = __builtin_amdgcn_mfma_f32_16x16x32_bf16(xa, cb0, acc0, 0, 0, 0);
            acc1 = __builtin_amdgcn_mfma_f32_16x16x32_bf16(xa, cb1, acc1, 0, 0, 0);
            acc2 = __builtin_amdgcn_mfma_f32_16x16x32_bf16(xa, cb2, acc2, 0, 0, 0);
            acc3 = __builtin_amdgcn_mfma_f32_16x16x32_bf16(xa, cb3, acc3, 0, 0, 0);

            cx0 = nx0; cx1 = nx1;
            cb0 = nb0; cb1 = nb1; cb2 = nb2; cb3 = nb3;
        }

        // D layout: col = lane&15 (t-col in n-tile), row = 4*kgrp + b (t-row)
        floatx4 accs[4] = {acc0, acc1, acc2, acc3};
        #pragma unroll
        for (int nt = 0; nt < 4; ++nt)
            #pragma unroll
            for (int b = 0; b < 4; ++b)
                red[wave][kgrp * 4 + b][nt * 16 + rrow] = accs[nt][b];
    }
    __syncthreads();
    #pragma unroll
    for (int e = threadIdx.x; e < 1024; e += 256) {
        int r = e >> 6, c = e & 63;
        tl[r][c] = f2bf(red[0][r][c] + red[1][r][c] + red[2][r][c] + red[3][r][c]);
    }
    __syncthreads();

    // ---------------- phase 2: out = (t @ B) * tw * 2, operand-swapped ----------------
    // t fragment (serves as MFMA *B*-operand): lane holds t[rrow][k], k = kofs+j
    short8 a0 = *(const short8*)&tl[rrow][kofs];
    short8 a1 = *(const short8*)&tl[rrow][32 + kofs];

    const float w = tw[rowbase + rrow] * 2.0f;   // one out-row per lane
    const size_t orow = (size_t)(rowbase + rrow) * 4096;

    // Fragment for (tile tt, nt, ks) at Bbf8[wave*8192 + tt*512 + (nt*2+ks)*64 + lane]
    const short8* bpw = (const short8*)Bbf + (size_t)wave * 8192 + lane;

    // prologue: tile 0's 8 fragments
    short8 cb[8];
    #pragma unroll
    for (int q = 0; q < 8; ++q) cb[q] = bpw[q * 64];

    #pragma unroll 2
    for (int tt = 0; tt < 16; ++tt) {
        // prefetch tile tt+1 (clamped; last iter re-loads tile 15, harmless)
        const int tn = (tt + 1 < 16) ? tt + 1 : 15;
        short8 nb[8];
        #pragma unroll
        for (int q = 0; q < 8; ++q) nb[q] = bpw[tn * 512 + q * 64];

        const int colbase = wave * 1024 + tt * 64;
        floatx4 acc[4] = {{0,0,0,0},{0,0,0,0},{0,0,0,0},{0,0,0,0}};
        #pragma unroll
        for (int nt = 0; nt < 4; ++nt) {
            // swapped: Bmat fragment as A-operand, t fragment as B-operand
            // -> lane holds out[row = rrow][cols = colbase + nt*16 + kgrp*4 + 0..3]
            acc[nt] = __builtin_amdgcn_mfma_f32_16x16x32_bf16(cb[nt * 2 + 0], a0, acc[nt], 0, 0, 0);
            acc[nt] = __builtin_amdgcn_mfma_f32_16x16x32_bf16(cb[nt * 2 + 1], a1, acc[nt], 0, 0, 0);
        }
        #pragma unroll
        for (int nt = 0; nt < 4; ++nt) {
            floatx4 v = acc[nt];
            v[0] *= w; v[1] *= w; v[2] *= w; v[3] *= w;
            float* p = out + orow + colbase + nt * 16 + kgrp * 4;
            __builtin_nontemporal_store(v, (floatx4*)p);
        }
        #pragma unroll
        for (int q = 0; q < 8; ++q) cb[q] = nb[q];
    }
}

extern "C" void kernel_launch(void* const* d_in, const int* in_sizes, int n_in,
                              void* d_out, int out_size, void* d_ws, size_t ws_size,
                              hipStream_t stream) {
    const float* x  = (const float*)d_in[0];   // (8,2048,4096)
    const float* tw = (const float*)d_in[1];   // (8,2048)
    const float* A  = (const float*)d_in[2];   // (4096,64)
    const float* B  = (const float*)d_in[3];   // (64,4096)
    float* out = (float*)d_out;                // (8,2048,4096) fp32

    short* Abf = (short*)d_ws;                 // 262144 bf16 = 512 KB
    short* Bbf = Abf + 262144;                 // 512 KB

    conv_ab<<<1024, 256, 0, stream>>>(A, B, Abf, Bbf);
    fused<<<1024, 256, 0, stream>>>(x, tw, Abf, Bbf, out);
}

// Round 8
// 110.293 us; speedup vs baseline: 1.0269x; 1.0269x over previous
//
#include <hip/hip_runtime.h>

typedef short short4v __attribute__((ext_vector_type(4)));
typedef short short8 __attribute__((ext_vector_type(8)));
typedef float floatx4 __attribute__((ext_vector_type(4)));

// Native bf16 conversion: compiler emits packed v_cvt_pk_bf16_f32 (RTNE).
__device__ __forceinline__ short f2bf(float f) {
    __bf16 h = (__bf16)f;
    return __builtin_bit_cast(short, h);
}

// Convert lora_A (4096x64) and lora_B (64x4096) fp32 -> bf16 in MFMA fragment
// layout for mfma_f32_16x16x32_bf16:
//   lane l holds elem[k][c] with c = l&15, k = 8*(l>>4) + j, j=0..7
__global__ __launch_bounds__(256) void conv_ab(
    const float* __restrict__ A, const float* __restrict__ B,
    short* __restrict__ Abf, short* __restrict__ Bbf) {
    int i = blockIdx.x * 256 + threadIdx.x;   // 0 .. 262143
    int j    = i & 7;
    int lane = (i >> 3) & 63;
    int hi   = i >> 9;                        // A: ks*4+nt ; B: ct*2+ks
    int krow = 8 * (lane >> 4) + j;
    int cc   = lane & 15;
    {   // A fragments
        int ks = hi >> 2, nt = hi & 3;
        int k = ks * 32 + krow;
        int c = nt * 16 + cc;
        Abf[i] = f2bf(A[(size_t)k * 64 + c]);
    }
    {   // B fragments
        int ct = hi >> 1, ks = hi & 1;
        int k = ks * 32 + krow;
        int c = ct * 16 + cc;
        Bbf[i] = f2bf(B[(size_t)k * 4096 + c]);
    }
}

// k1: t2[p][16384][64] (bf16, p = K-half partials) = partial x @ A
// grid (1024, 2) x 4 waves: blockIdx.x = 16-row group, blockIdx.y = K-half.
// Wave owns K-slice 512 (16 iters, 1-ahead prefetch), 4 MFMA chains;
// cross-wave LDS reduce -> bf16 partial. 16.6 KB LDS -> 8 blocks/CU (32 w/CU).
__global__ __launch_bounds__(256, 4) void k1_xA(
    const float* __restrict__ x, const float* __restrict__ tw,
    const short* __restrict__ Abf, short* __restrict__ t2) {
    __shared__ float red[4][16][65];

    const int lane = threadIdx.x & 63;
    const int wave = threadIdx.x >> 6;
    const int rowbase = blockIdx.x * 16;
    const int rrow = lane & 15;
    const int kgrp = lane >> 4;
    const int kofs = kgrp * 8;
    const int kbase = blockIdx.y * 2048 + wave * 512;

    {
        const int row = rowbase + rrow;
        const bool active = (tw[row] != 0.0f);
        const floatx4* xv = (const floatx4*)(x + (size_t)row * 4096 + kbase + kofs);
        // Abf8[(ksg*4+nt)*64 + lane], ksg = kbase/32 + ks
        const short8* ap = (const short8*)Abf + ((size_t)(kbase >> 5) * 256) + lane;

        floatx4 acc0 = {0,0,0,0}, acc1 = {0,0,0,0}, acc2 = {0,0,0,0}, acc3 = {0,0,0,0};

        floatx4 cx0 = {0,0,0,0}, cx1 = {0,0,0,0};
        if (active) { cx0 = xv[0]; cx1 = xv[1]; }
        short8 cb0 = ap[0], cb1 = ap[64], cb2 = ap[128], cb3 = ap[192];

        #pragma unroll 4
        for (int ks = 0; ks < 16; ++ks) {
            const int kn = (ks + 1 < 16) ? ks + 1 : 15;
            floatx4 nx0 = {0,0,0,0}, nx1 = {0,0,0,0};
            if (active) { nx0 = xv[kn * 8]; nx1 = xv[kn * 8 + 1]; }
            short8 nb0 = ap[kn * 256 + 0 * 64];
            short8 nb1 = ap[kn * 256 + 1 * 64];
            short8 nb2 = ap[kn * 256 + 2 * 64];
            short8 nb3 = ap[kn * 256 + 3 * 64];

            short8 xa;
            xa[0] = f2bf(cx0[0]); xa[1] = f2bf(cx0[1]);
            xa[2] = f2bf(cx0[2]); xa[3] = f2bf(cx0[3]);
            xa[4] = f2bf(cx1[0]); xa[5] = f2bf(cx1[1]);
            xa[6] = f2bf(cx1[2]); xa[7] = f2bf(cx1[3]);

            acc0 = __builtin_amdgcn_mfma_f32_16x16x32_bf16(xa, cb0, acc0, 0, 0, 0);
            acc1 = __builtin_amdgcn_mfma_f32_16x16x32_bf16(xa, cb1, acc1, 0, 0, 0);
            acc2 = __builtin_amdgcn_mfma_f32_16x16x32_bf16(xa, cb2, acc2, 0, 0, 0);
            acc3 = __builtin_amdgcn_mfma_f32_16x16x32_bf16(xa, cb3, acc3, 0, 0, 0);

            cx0 = nx0; cx1 = nx1;
            cb0 = nb0; cb1 = nb1; cb2 = nb2; cb3 = nb3;
        }

        floatx4 accs[4] = {acc0, acc1, acc2, acc3};
        #pragma unroll
        for (int nt = 0; nt < 4; ++nt)
            #pragma unroll
            for (int b = 0; b < 4; ++b)
                red[wave][kgrp * 4 + b][nt * 16 + rrow] = accs[nt][b];
    }
    __syncthreads();

    // 256 threads cover 16x64: thread -> (r = tid>>4, 4 cols), short4 store
    {
        const int r = threadIdx.x >> 4;
        const int c = (threadIdx.x & 15) * 4;
        short4v v;
        #pragma unroll
        for (int q = 0; q < 4; ++q)
            v[q] = f2bf(red[0][r][c + q] + red[1][r][c + q] +
                        red[2][r][c + q] + red[3][r][c + q]);
        short* dst = t2 + ((size_t)blockIdx.y * 16384 + rowbase + r) * 64 + c;
        *(short4v*)dst = v;
    }
}

// k2: out = ((t2[0]+t2[1]) @ B) * tw * 2, operand-swapped MFMA.
// 16384 blocks x 4 waves, NO LDS/barriers: block = 1 row-group x 4 col-tiles,
// wave = 16 rows x 64 cols. TLP (64 blocks/CU queued) hides L2 latency.
__global__ __launch_bounds__(256, 4) void k2_tB(
    const short* __restrict__ t2, const float* __restrict__ tw,
    const short* __restrict__ Bbf, float* __restrict__ out) {
    const int lane = threadIdx.x & 63;
    const int wave = threadIdx.x >> 6;
    const int rg = blockIdx.x >> 4;
    const int cs = blockIdx.x & 15;
    const int rowbase = rg * 16;
    const int colbase = cs * 256 + wave * 64;
    const int rrow = lane & 15;
    const int kgrp = lane >> 4;
    const int kofs = kgrp * 8;

    // t fragments (MFMA B-operand after swap): lane holds t[rrow][kofs+j]
    const short* t0 = t2 + (size_t)(rowbase + rrow) * 64 + kofs;
    const short* t1 = t0 + (size_t)16384 * 64;
    short8 a00 = *(const short8*)t0;
    short8 a01 = *(const short8*)(t0 + 32);
    short8 a10 = *(const short8*)t1;
    short8 a11 = *(const short8*)(t1 + 32);

    // B fragments (MFMA A-operand): Bbf8[(ct*2+ks)*64 + lane], ct = col/16
    const short8* bp = (const short8*)Bbf + (size_t)(colbase >> 4) * 128 + lane;

    const float w = tw[rowbase + rrow] * 2.0f;
    const size_t orow = (size_t)(rowbase + rrow) * 4096;

    #pragma unroll
    for (int nt = 0; nt < 4; ++nt) {
        short8 b0 = bp[(nt * 2 + 0) * 64];
        short8 b1 = bp[(nt * 2 + 1) * 64];
        floatx4 acc = {0, 0, 0, 0};
        // swapped: lane holds out[rrow][colbase + nt*16 + kgrp*4 + 0..3]
        acc = __builtin_amdgcn_mfma_f32_16x16x32_bf16(b0, a00, acc, 0, 0, 0);
        acc = __builtin_amdgcn_mfma_f32_16x16x32_bf16(b1, a01, acc, 0, 0, 0);
        acc = __builtin_amdgcn_mfma_f32_16x16x32_bf16(b0, a10, acc, 0, 0, 0);
        acc = __builtin_amdgcn_mfma_f32_16x16x32_bf16(b1, a11, acc, 0, 0, 0);

        acc[0] *= w; acc[1] *= w; acc[2] *= w; acc[3] *= w;
        float* p = out + orow + colbase + nt * 16 + kgrp * 4;
        __builtin_nontemporal_store(acc, (floatx4*)p);
    }
}

extern "C" void kernel_launch(void* const* d_in, const int* in_sizes, int n_in,
                              void* d_out, int out_size, void* d_ws, size_t ws_size,
                              hipStream_t stream) {
    const float* x  = (const float*)d_in[0];   // (8,2048,4096)
    const float* tw = (const float*)d_in[1];   // (8,2048)
    const float* A  = (const float*)d_in[2];   // (4096,64)
    const float* B  = (const float*)d_in[3];   // (64,4096)
    float* out = (float*)d_out;                // (8,2048,4096) fp32

    short* Abf = (short*)d_ws;                 // 262144 bf16 = 512 KB
    short* Bbf = Abf + 262144;                 // 512 KB
    short* t2  = Bbf + 262144;                 // 2 x 16384 x 64 bf16 = 4 MB

    conv_ab<<<1024, 256, 0, stream>>>(A, B, Abf, Bbf);
    k1_xA<<<dim3(1024, 2), 256, 0, stream>>>(x, tw, Abf, t2);
    k2_tB<<<16384, 256, 0, stream>>>(t2, tw, Bbf, out);
}

// Round 9
// 94.581 us; speedup vs baseline: 1.1974x; 1.1661x over previous
//
#include <hip/hip_runtime.h>

typedef short short4v __attribute__((ext_vector_type(4)));
typedef short short8 __attribute__((ext_vector_type(8)));
typedef float floatx4 __attribute__((ext_vector_type(4)));

// Native bf16 conversion: compiler emits packed v_cvt_pk_bf16_f32 (RTNE).
__device__ __forceinline__ short f2bf(float f) {
    __bf16 h = (__bf16)f;
    return __builtin_bit_cast(short, h);
}
__device__ __forceinline__ float bf2f(short s) {
    unsigned u = ((unsigned)(unsigned short)s) << 16;
    return __builtin_bit_cast(float, u);
}

// Convert lora_A (4096x64) and lora_B (64x4096) fp32 -> bf16 in MFMA fragment
// layout for mfma_f32_16x16x32_bf16:
//   lane l holds elem[k][c] with c = l&15, k = 8*(l>>4) + j, j=0..7
__global__ __launch_bounds__(256) void conv_ab(
    const float* __restrict__ A, const float* __restrict__ B,
    short* __restrict__ Abf, short* __restrict__ Bbf) {
    int i = blockIdx.x * 256 + threadIdx.x;   // 0 .. 262143
    int j    = i & 7;
    int lane = (i >> 3) & 63;
    int hi   = i >> 9;                        // A: ks*4+nt ; B: ct*2+ks
    int krow = 8 * (lane >> 4) + j;
    int cc   = lane & 15;
    {   // A fragments
        int ks = hi >> 2, nt = hi & 3;
        Abf[i] = f2bf(A[(size_t)(ks * 32 + krow) * 64 + nt * 16 + cc]);
    }
    {   // B fragments
        int ct = hi >> 1, ks = hi & 1;
        Bbf[i] = f2bf(B[(size_t)(ks * 32 + krow) * 4096 + ct * 16 + cc]);
    }
}

// k1: 8 bf16 split-K partials of t = x @ A.  Grid (1024, 2) x 4 waves.
// Wave w of block (bx, by) owns rows bx*16..+15, ksplit p = by*4+w (K-slice 512,
// 16 iters, 1-ahead prefetch). Operand-SWAPPED mfma -> lane holds 4 consecutive
// t-cols of ONE row -> direct 8B stores. No LDS, no barriers.
__global__ __launch_bounds__(256, 4) void k1_xA(
    const float* __restrict__ x, const float* __restrict__ tw,
    const short* __restrict__ Abf, short* __restrict__ t8) {
    const int lane = threadIdx.x & 63;
    const int wave = threadIdx.x >> 6;
    const int rowbase = blockIdx.x * 16;
    const int rrow = lane & 15;
    const int kgrp = lane >> 4;
    const int kofs = kgrp * 8;
    const int p = blockIdx.y * 4 + wave;      // ksplit 0..7
    const int kbase = p * 512;

    const int row = rowbase + rrow;
    const bool active = (tw[row] != 0.0f);
    const floatx4* xv = (const floatx4*)(x + (size_t)row * 4096 + kbase + kofs);
    // Abf8[(ksg*4+nt)*64 + lane], ksg = kbase/32 + ks
    const short8* ap = (const short8*)Abf + ((size_t)(kbase >> 5) * 256) + lane;

    floatx4 acc0 = {0,0,0,0}, acc1 = {0,0,0,0}, acc2 = {0,0,0,0}, acc3 = {0,0,0,0};

    floatx4 cx0 = {0,0,0,0}, cx1 = {0,0,0,0};
    if (active) { cx0 = xv[0]; cx1 = xv[1]; }
    short8 cb0 = ap[0], cb1 = ap[64], cb2 = ap[128], cb3 = ap[192];

    #pragma unroll 4
    for (int ks = 0; ks < 16; ++ks) {
        const int kn = (ks + 1 < 16) ? ks + 1 : 15;
        floatx4 nx0 = {0,0,0,0}, nx1 = {0,0,0,0};
        if (active) { nx0 = xv[kn * 8]; nx1 = xv[kn * 8 + 1]; }
        short8 nb0 = ap[kn * 256 + 0 * 64];
        short8 nb1 = ap[kn * 256 + 1 * 64];
        short8 nb2 = ap[kn * 256 + 2 * 64];
        short8 nb3 = ap[kn * 256 + 3 * 64];

        short8 xa;
        xa[0] = f2bf(cx0[0]); xa[1] = f2bf(cx0[1]);
        xa[2] = f2bf(cx0[2]); xa[3] = f2bf(cx0[3]);
        xa[4] = f2bf(cx1[0]); xa[5] = f2bf(cx1[1]);
        xa[6] = f2bf(cx1[2]); xa[7] = f2bf(cx1[3]);

        // swapped: A-matrix fragment as A-operand, x fragment as B-operand.
        // D[m][n] = sum_k A[kbase+k][nt*16+m] * x[rowbase+n][kbase+k]
        //         = t[rowbase+n][nt*16+m]
        acc0 = __builtin_amdgcn_mfma_f32_16x16x32_bf16(cb0, xa, acc0, 0, 0, 0);
        acc1 = __builtin_amdgcn_mfma_f32_16x16x32_bf16(cb1, xa, acc1, 0, 0, 0);
        acc2 = __builtin_amdgcn_mfma_f32_16x16x32_bf16(cb2, xa, acc2, 0, 0, 0);
        acc3 = __builtin_amdgcn_mfma_f32_16x16x32_bf16(cb3, xa, acc3, 0, 0, 0);

        cx0 = nx0; cx1 = nx1;
        cb0 = nb0; cb1 = nb1; cb2 = nb2; cb3 = nb3;
    }

    // D layout: n = lane&15 (token row), m = 4*kgrp + b (t-col within n-tile)
    // -> lane holds t_p[row][nt*16 + kgrp*4 + 0..3]: contiguous 8B per nt.
    short* tp = t8 + (size_t)p * (16384 * 64) + (size_t)row * 64 + kgrp * 4;
    floatx4 accs[4] = {acc0, acc1, acc2, acc3};
    #pragma unroll
    for (int nt = 0; nt < 4; ++nt) {
        short4v v;
        v[0] = f2bf(accs[nt][0]); v[1] = f2bf(accs[nt][1]);
        v[2] = f2bf(accs[nt][2]); v[3] = f2bf(accs[nt][3]);
        *(short4v*)(tp + nt * 16) = v;
    }
}

// k1.5: t = sum of 8 bf16 partials (f32 accumulate). 1M elems / 4 per thread.
__global__ __launch_bounds__(256) void k1_sum(
    const short* __restrict__ t8, short* __restrict__ t) {
    const int i = blockIdx.x * 256 + threadIdx.x;   // 0 .. 262143
    const size_t off = (size_t)i * 4;
    float s0 = 0.f, s1 = 0.f, s2 = 0.f, s3 = 0.f;
    #pragma unroll
    for (int p = 0; p < 8; ++p) {
        short4v v = *(const short4v*)(t8 + (size_t)p * (16384 * 64) + off);
        s0 += bf2f(v[0]); s1 += bf2f(v[1]); s2 += bf2f(v[2]); s3 += bf2f(v[3]);
    }
    short4v r;
    r[0] = f2bf(s0); r[1] = f2bf(s1); r[2] = f2bf(s2); r[3] = f2bf(s3);
    *(short4v*)(t + off) = r;
}

// k2: out = (t @ B) * tw * 2, operand-swapped MFMA, LDS-staged epilogue.
// 16384 blocks x 4 waves: block = 16 rows x 256 cols; wave w computes cols
// [64w,64w+64), stages f32 tile in LDS, then row-linear NT float4 stores
// (lanes 0-15 cover 256B contiguous per row).
__global__ __launch_bounds__(256, 4) void k2_tB(
    const short* __restrict__ t, const float* __restrict__ tw,
    const short* __restrict__ Bbf, float* __restrict__ out) {
    __shared__ float tile[16][257];       // +1 float pad (16.4 KB)

    const int lane = threadIdx.x & 63;
    const int wave = threadIdx.x >> 6;
    const int rg = blockIdx.x >> 4;
    const int cs = blockIdx.x & 15;
    const int rowbase = rg * 16;
    const int colblk = cs * 256;
    const int rrow = lane & 15;
    const int kgrp = lane >> 4;
    const int kofs = kgrp * 8;

    // t fragment (MFMA B-operand): lane holds t[rowbase+rrow][kofs+j]
    const short* t0 = t + (size_t)(rowbase + rrow) * 64 + kofs;
    short8 a0 = *(const short8*)t0;
    short8 a1 = *(const short8*)(t0 + 32);

    // B fragments (MFMA A-operand): Bbf8[(ct*2+ks)*64 + lane], ct = col/16
    const short8* bp = (const short8*)Bbf + (size_t)((colblk + wave * 64) >> 4) * 128 + lane;

    const float w = tw[rowbase + rrow] * 2.0f;

    #pragma unroll
    for (int nt = 0; nt < 4; ++nt) {
        short8 b0 = bp[(nt * 2 + 0) * 64];
        short8 b1 = bp[(nt * 2 + 1) * 64];
        floatx4 acc = {0, 0, 0, 0};
        // swapped: lane holds out[rrow][wave*64 + nt*16 + kgrp*4 + 0..3]
        acc = __builtin_amdgcn_mfma_f32_16x16x32_bf16(b0, a0, acc, 0, 0, 0);
        acc = __builtin_amdgcn_mfma_f32_16x16x32_bf16(b1, a1, acc, 0, 0, 0);
        acc[0] *= w; acc[1] *= w; acc[2] *= w; acc[3] *= w;
        *(floatx4*)&tile[rrow][wave * 64 + nt * 16 + kgrp * 4] = acc;
    }
    __syncthreads();

    // row-linear write-out: wave w -> rows 4w..4w+3; lane l -> row 4w+(l>>4),
    // 16B chunk (l&15)*16B within each 64-float column group q.
    const int orow_i = 4 * wave + (lane >> 4);
    float* orow = out + (size_t)(rowbase + orow_i) * 4096 + colblk;
    #pragma unroll
    for (int q = 0; q < 4; ++q) {
        const int c = q * 64 + rrow * 4;
        floatx4 v = *(const floatx4*)&tile[orow_i][c];
        __builtin_nontemporal_store(v, (floatx4*)(orow + c));
    }
}

extern "C" void kernel_launch(void* const* d_in, const int* in_sizes, int n_in,
                              void* d_out, int out_size, void* d_ws, size_t ws_size,
                              hipStream_t stream) {
    const float* x  = (const float*)d_in[0];   // (8,2048,4096)
    const float* tw = (const float*)d_in[1];   // (8,2048)
    const float* A  = (const float*)d_in[2];   // (4096,64)
    const float* B  = (const float*)d_in[3];   // (64,4096)
    float* out = (float*)d_out;                // (8,2048,4096) fp32

    short* Abf = (short*)d_ws;                 // 512 KB
    short* Bbf = Abf + 262144;                 // 512 KB
    short* t8  = Bbf + 262144;                 // 8 x 16384 x 64 bf16 = 16 MB
    short* t   = t8 + (size_t)8 * 16384 * 64;  // 2 MB

    conv_ab<<<1024, 256, 0, stream>>>(A, B, Abf, Bbf);
    k1_xA<<<dim3(1024, 2), 256, 0, stream>>>(x, tw, Abf, t8);
    k1_sum<<<1024, 256, 0, stream>>>(t8, t);
    k2_tB<<<16384, 256, 0, stream>>>(t, tw, Bbf, out);
}

// Round 10
// 93.102 us; speedup vs baseline: 1.2165x; 1.0159x over previous
//
#include <hip/hip_runtime.h>

typedef short short4v __attribute__((ext_vector_type(4)));
typedef short short8 __attribute__((ext_vector_type(8)));
typedef float floatx4 __attribute__((ext_vector_type(4)));

// Native bf16 conversion: compiler emits packed v_cvt_pk_bf16_f32 (RTNE).
__device__ __forceinline__ short f2bf(float f) {
    __bf16 h = (__bf16)f;
    return __builtin_bit_cast(short, h);
}
__device__ __forceinline__ float bf2f(short s) {
    unsigned u = ((unsigned)(unsigned short)s) << 16;
    return __builtin_bit_cast(float, u);
}

// Convert lora_A (4096x64) and lora_B (64x4096) fp32 -> bf16 in MFMA fragment
// layout for mfma_f32_16x16x32_bf16:
//   lane l holds elem[k][c] with c = l&15, k = 8*(l>>4) + j, j=0..7
__global__ __launch_bounds__(256) void conv_ab(
    const float* __restrict__ A, const float* __restrict__ B,
    short* __restrict__ Abf, short* __restrict__ Bbf) {
    int i = blockIdx.x * 256 + threadIdx.x;   // 0 .. 262143
    int j    = i & 7;
    int lane = (i >> 3) & 63;
    int hi   = i >> 9;                        // A: ks*4+nt ; B: ct*2+ks
    int krow = 8 * (lane >> 4) + j;
    int cc   = lane & 15;
    {   // A fragments
        int ks = hi >> 2, nt = hi & 3;
        Abf[i] = f2bf(A[(size_t)(ks * 32 + krow) * 64 + nt * 16 + cc]);
    }
    {   // B fragments
        int ct = hi >> 1, ks = hi & 1;
        Bbf[i] = f2bf(B[(size_t)(ks * 32 + krow) * 4096 + ct * 16 + cc]);
    }
}

// k1: 8 bf16 split-K partials of t = x @ A.  Grid (1024, 2) x 4 waves.
// Wave w of block (bx, by) owns rows bx*16..+15, ksplit p = by*4+w (K-slice 512,
// 16 iters). 2-deep rotating register pipeline: slot s=ks&1 holds iter ks's
// operands; refilled with iter ks+2 after local-copy, before the MFMAs.
// Operand-SWAPPED mfma -> lane holds 4 consecutive t-cols of ONE row ->
// direct 8B stores. No LDS, no barriers.
__global__ __launch_bounds__(256, 4) void k1_xA(
    const float* __restrict__ x, const float* __restrict__ tw,
    const short* __restrict__ Abf, short* __restrict__ t8) {
    const int lane = threadIdx.x & 63;
    const int wave = threadIdx.x >> 6;
    const int rowbase = blockIdx.x * 16;
    const int rrow = lane & 15;
    const int kgrp = lane >> 4;
    const int p = blockIdx.y * 4 + wave;      // ksplit 0..7
    const int kbase = p * 512;

    const int row = rowbase + rrow;
    const bool active = (tw[row] != 0.0f);
    const floatx4* xv = (const floatx4*)(x + (size_t)row * 4096 + kbase + kgrp * 8);
    // Abf8[(ksg*4+nt)*64 + lane], ksg = kbase/32 + ks
    const short8* ap = (const short8*)Abf + ((size_t)(kbase >> 5) * 256) + lane;

    floatx4 acc0 = {0,0,0,0}, acc1 = {0,0,0,0}, acc2 = {0,0,0,0}, acc3 = {0,0,0,0};

    floatx4 px[2][2];
    short8  pb[2][4];
    #pragma unroll
    for (int s = 0; s < 2; ++s) {
        px[s][0] = (floatx4){0,0,0,0};
        px[s][1] = (floatx4){0,0,0,0};
        if (active) { px[s][0] = xv[s * 8]; px[s][1] = xv[s * 8 + 1]; }
        pb[s][0] = ap[s * 256 + 0 * 64];
        pb[s][1] = ap[s * 256 + 1 * 64];
        pb[s][2] = ap[s * 256 + 2 * 64];
        pb[s][3] = ap[s * 256 + 3 * 64];
    }

    #pragma unroll
    for (int ks = 0; ks < 16; ++ks) {
        const int s = ks & 1;
        // consume slot s into locals
        short8 xa;
        xa[0] = f2bf(px[s][0][0]); xa[1] = f2bf(px[s][0][1]);
        xa[2] = f2bf(px[s][0][2]); xa[3] = f2bf(px[s][0][3]);
        xa[4] = f2bf(px[s][1][0]); xa[5] = f2bf(px[s][1][1]);
        xa[6] = f2bf(px[s][1][2]); xa[7] = f2bf(px[s][1][3]);
        short8 b0 = pb[s][0], b1 = pb[s][1], b2 = pb[s][2], b3 = pb[s][3];

        // refill slot s with iter ks+2 (issues before the MFMAs below;
        // lands ~2 iterations later). Inactive lanes keep their zeros.
        if (ks + 2 < 16) {
            if (active) { px[s][0] = xv[(ks + 2) * 8]; px[s][1] = xv[(ks + 2) * 8 + 1]; }
            pb[s][0] = ap[(ks + 2) * 256 + 0 * 64];
            pb[s][1] = ap[(ks + 2) * 256 + 1 * 64];
            pb[s][2] = ap[(ks + 2) * 256 + 2 * 64];
            pb[s][3] = ap[(ks + 2) * 256 + 3 * 64];
        }

        // swapped: A-matrix fragment as A-operand, x fragment as B-operand.
        // D[m][n] = sum_k A[kbase+k][nt*16+m] * x[rowbase+n][kbase+k]
        acc0 = __builtin_amdgcn_mfma_f32_16x16x32_bf16(b0, xa, acc0, 0, 0, 0);
        acc1 = __builtin_amdgcn_mfma_f32_16x16x32_bf16(b1, xa, acc1, 0, 0, 0);
        acc2 = __builtin_amdgcn_mfma_f32_16x16x32_bf16(b2, xa, acc2, 0, 0, 0);
        acc3 = __builtin_amdgcn_mfma_f32_16x16x32_bf16(b3, xa, acc3, 0, 0, 0);
    }

    // D layout: n = lane&15 (token row), m = 4*kgrp + b (t-col within n-tile)
    // -> lane holds t_p[row][nt*16 + kgrp*4 + 0..3]: contiguous 8B per nt.
    short* tp = t8 + (size_t)p * (16384 * 64) + (size_t)row * 64 + kgrp * 4;
    floatx4 accs[4] = {acc0, acc1, acc2, acc3};
    #pragma unroll
    for (int nt = 0; nt < 4; ++nt) {
        short4v v;
        v[0] = f2bf(accs[nt][0]); v[1] = f2bf(accs[nt][1]);
        v[2] = f2bf(accs[nt][2]); v[3] = f2bf(accs[nt][3]);
        *(short4v*)(tp + nt * 16) = v;
    }
}

// k1.5: t = sum of 8 bf16 partials (f32 accumulate). 1M elems / 4 per thread.
__global__ __launch_bounds__(256) void k1_sum(
    const short* __restrict__ t8, short* __restrict__ t) {
    const int i = blockIdx.x * 256 + threadIdx.x;   // 0 .. 262143
    const size_t off = (size_t)i * 4;
    float s0 = 0.f, s1 = 0.f, s2 = 0.f, s3 = 0.f;
    #pragma unroll
    for (int p = 0; p < 8; ++p) {
        short4v v = *(const short4v*)(t8 + (size_t)p * (16384 * 64) + off);
        s0 += bf2f(v[0]); s1 += bf2f(v[1]); s2 += bf2f(v[2]); s3 += bf2f(v[3]);
    }
    short4v r;
    r[0] = f2bf(s0); r[1] = f2bf(s1); r[2] = f2bf(s2); r[3] = f2bf(s3);
    *(short4v*)(t + off) = r;
}

// k2: out = (t @ B) * tw * 2, operand-swapped MFMA, LDS-staged epilogue.
// 16384 blocks x 4 waves: block = 16 rows x 256 cols; wave w computes cols
// [64w,64w+64), stages f32 tile in LDS, then row-linear NT float4 stores
// (lanes 0-15 cover 256B contiguous per row).
__global__ __launch_bounds__(256, 4) void k2_tB(
    const short* __restrict__ t, const float* __restrict__ tw,
    const short* __restrict__ Bbf, float* __restrict__ out) {
    __shared__ float tile[16][257];       // +1 float pad (16.4 KB)

    const int lane = threadIdx.x & 63;
    const int wave = threadIdx.x >> 6;
    const int rg = blockIdx.x >> 4;
    const int cs = blockIdx.x & 15;
    const int rowbase = rg * 16;
    const int colblk = cs * 256;
    const int rrow = lane & 15;
    const int kgrp = lane >> 4;
    const int kofs = kgrp * 8;

    // t fragment (MFMA B-operand): lane holds t[rowbase+rrow][kofs+j]
    const short* t0 = t + (size_t)(rowbase + rrow) * 64 + kofs;
    short8 a0 = *(const short8*)t0;
    short8 a1 = *(const short8*)(t0 + 32);

    // B fragments (MFMA A-operand): Bbf8[(ct*2+ks)*64 + lane], ct = col/16
    const short8* bp = (const short8*)Bbf + (size_t)((colblk + wave * 64) >> 4) * 128 + lane;

    const float w = tw[rowbase + rrow] * 2.0f;

    #pragma unroll
    for (int nt = 0; nt < 4; ++nt) {
        short8 b0 = bp[(nt * 2 + 0) * 64];
        short8 b1 = bp[(nt * 2 + 1) * 64];
        floatx4 acc = {0, 0, 0, 0};
        // swapped: lane holds out[rrow][wave*64 + nt*16 + kgrp*4 + 0..3]
        acc = __builtin_amdgcn_mfma_f32_16x16x32_bf16(b0, a0, acc, 0, 0, 0);
        acc = __builtin_amdgcn_mfma_f32_16x16x32_bf16(b1, a1, acc, 0, 0, 0);
        acc[0] *= w; acc[1] *= w; acc[2] *= w; acc[3] *= w;
        *(floatx4*)&tile[rrow][wave * 64 + nt * 16 + kgrp * 4] = acc;
    }
    __syncthreads();

    // row-linear write-out: wave w -> rows 4w..4w+3; lane l -> row 4w+(l>>4),
    // 16B chunk (l&15)*16B within each 64-float column group q.
    const int orow_i = 4 * wave + (lane >> 4);
    float* orow = out + (size_t)(rowbase + orow_i) * 4096 + colblk;
    #pragma unroll
    for (int q = 0; q < 4; ++q) {
        const int c = q * 64 + rrow * 4;
        floatx4 v = *(const floatx4*)&tile[orow_i][c];
        __builtin_nontemporal_store(v, (floatx4*)(orow + c));
    }
}

extern "C" void kernel_launch(void* const* d_in, const int* in_sizes, int n_in,
                              void* d_out, int out_size, void* d_ws, size_t ws_size,
                              hipStream_t stream) {
    const float* x  = (const float*)d_in[0];   // (8,2048,4096)
    const float* tw = (const float*)d_in[1];   // (8,2048)
    const float* A  = (const float*)d_in[2];   // (4096,64)
    const float* B  = (const float*)d_in[3];   // (64,4096)
    float* out = (float*)d_out;                // (8,2048,4096) fp32

    short* Abf = (short*)d_ws;                 // 512 KB
    short* Bbf = Abf + 262144;                 // 512 KB
    short* t8  = Bbf + 262144;                 // 8 x 16384 x 64 bf16 = 16 MB
    short* t   = t8 + (size_t)8 * 16384 * 64;  // 2 MB

    conv_ab<<<1024, 256, 0, stream>>>(A, B, Abf, Bbf);
    k1_xA<<<dim3(1024, 2), 256, 0, stream>>>(x, tw, Abf, t8);
    k1_sum<<<1024, 256, 0, stream>>>(t8, t);
    k2_tB<<<16384, 256, 0, stream>>>(t, tw, Bbf, out);
}